// Round 3
// baseline (273.249 us; speedup 1.0000x reference)
//
#include <hip/hip_runtime.h>
#include <math.h>

#define D_FEAT 128
#define D_DOT  4
#define TILE   256   // rows (edges/nodes) per block tile
#define PAD    9     // LDS row stride in float4s; 9 % 8 == 1 -> conflict-free

// Shared tile pattern: stage quarter-rows (8 float4 cols) of 256 rows into LDS
// with coalesced global loads, then each lane accumulates its own row from LDS
// (no cross-lane ops). W lives in LDS, read at wave-uniform addrs (broadcast).

__global__ __launch_bounds__(256) void node_proj_kernel(
    const float* __restrict__ n,
    const float* __restrict__ W,
    float* __restrict__ pn,
    int n_nodes)
{
    __shared__ float4 xt[TILE * PAD];   // 36864 B
    __shared__ float4 Wl[D_DOT * 32];   // 2048 B: Wl[k*32 + c] = W[k][4c..4c+3]

    const int t = threadIdx.x;
    if (t < 128) Wl[t] = reinterpret_cast<const float4*>(W)[t];

    const int tile_base = blockIdx.x * TILE;
    const int last = n_nodes - 1;
    const float4* n4 = reinterpret_cast<const float4*>(n);

    float a0 = 0.f, a1 = 0.f, a2 = 0.f, a3 = 0.f;
#pragma unroll
    for (int q = 0; q < 4; ++q) {
        __syncthreads();   // also covers Wl init at q==0
#pragma unroll
        for (int i = 0; i < 8; ++i) {
            const int s = i * 256 + t;
            const int r = s >> 3;        // row within tile
            const int j = s & 7;         // float4 col within phase
            int row = tile_base + r; if (row > last) row = last;
            xt[r * PAD + j] = n4[(size_t)row * 32 + q * 8 + j];
        }
        __syncthreads();
#pragma unroll
        for (int j = 0; j < 8; ++j) {
            const float4 x = xt[t * PAD + j];
            const int c = q * 8 + j;
            const float4 w0 = Wl[c], w1 = Wl[32 + c], w2 = Wl[64 + c], w3 = Wl[96 + c];
            a0 += x.x * w0.x + x.y * w0.y + x.z * w0.z + x.w * w0.w;
            a1 += x.x * w1.x + x.y * w1.y + x.z * w1.z + x.w * w1.w;
            a2 += x.x * w2.x + x.y * w2.y + x.z * w2.z + x.w * w2.w;
            a3 += x.x * w3.x + x.y * w3.y + x.z * w3.z + x.w * w3.w;
        }
    }
    const int row = tile_base + t;
    if (row < n_nodes)
        reinterpret_cast<float4*>(pn)[row] = make_float4(a0, a1, a2, a3);
}

__global__ __launch_bounds__(256) void edge_score_kernel(
    const float* __restrict__ e,
    const float* __restrict__ W,
    const float* __restrict__ bias,
    const float* __restrict__ pn,
    const int* __restrict__ src_idx,
    const int* __restrict__ dst_idx,
    float* __restrict__ out,
    int n_edges)
{
    __shared__ float4 xt[TILE * PAD];
    __shared__ float4 Wl[D_DOT * 32];

    const int t = threadIdx.x;
    if (t < 128) Wl[t] = reinterpret_cast<const float4*>(W)[t];

    const int tile_base = blockIdx.x * TILE;
    const int last = n_edges - 1;
    const float4* e4 = reinterpret_cast<const float4*>(e);

    float a0 = 0.f, a1 = 0.f, a2 = 0.f, a3 = 0.f;
#pragma unroll
    for (int q = 0; q < 4; ++q) {
        __syncthreads();
#pragma unroll
        for (int i = 0; i < 8; ++i) {
            const int s = i * 256 + t;
            const int r = s >> 3;
            const int j = s & 7;
            int row = tile_base + r; if (row > last) row = last;
            xt[r * PAD + j] = e4[(size_t)row * 32 + q * 8 + j];
        }
        __syncthreads();
#pragma unroll
        for (int j = 0; j < 8; ++j) {
            const float4 x = xt[t * PAD + j];
            const int c = q * 8 + j;
            const float4 w0 = Wl[c], w1 = Wl[32 + c], w2 = Wl[64 + c], w3 = Wl[96 + c];
            a0 += x.x * w0.x + x.y * w0.y + x.z * w0.z + x.w * w0.w;
            a1 += x.x * w1.x + x.y * w1.y + x.z * w1.z + x.w * w1.w;
            a2 += x.x * w2.x + x.y * w2.y + x.z * w2.z + x.w * w2.w;
            a3 += x.x * w3.x + x.y * w3.y + x.z * w3.z + x.w * w3.w;
        }
    }

    const int edge = tile_base + t;
    if (edge < n_edges) {
        const float b0 = bias[0], b1 = bias[1], b2 = bias[2], b3 = bias[3];
        const int s = src_idx[edge];
        const int d = dst_idx[edge];
        const float4 ps = reinterpret_cast<const float4*>(pn)[s];
        const float4 pd = reinterpret_cast<const float4*>(pn)[d];
        float hs, hd, dot = 0.f;
        hs = 0.5f * (ps.x + a0) + b0; hd = 0.5f * (pd.x + a0) + b0; dot += hs * hd;
        hs = 0.5f * (ps.y + a1) + b1; hd = 0.5f * (pd.y + a1) + b1; dot += hs * hd;
        hs = 0.5f * (ps.z + a2) + b2; hd = 0.5f * (pd.z + a2) + b2; dot += hs * hd;
        hs = 0.5f * (ps.w + a3) + b3; hd = 0.5f * (pd.w + a3) + b3; dot += hs * hd;
        out[edge] = 1.0f / (1.0f + __expf(-dot));
    }
}

extern "C" void kernel_launch(void* const* d_in, const int* in_sizes, int n_in,
                              void* d_out, int out_size, void* d_ws, size_t ws_size,
                              hipStream_t stream) {
    const float* n    = (const float*)d_in[0];
    const float* e    = (const float*)d_in[1];
    const float* W    = (const float*)d_in[2];
    const float* bias = (const float*)d_in[3];
    const int*   src  = (const int*)d_in[4];
    const int*   dst  = (const int*)d_in[5];
    float* out = (float*)d_out;

    const int n_nodes = in_sizes[0] / D_FEAT;
    const int n_edges = in_sizes[1] / D_FEAT;

    float* pn = (float*)d_ws;  // n_nodes * 4 floats

    const int nblk = (n_nodes + TILE - 1) / TILE;
    const int eblk = (n_edges + TILE - 1) / TILE;
    node_proj_kernel<<<nblk, 256, 0, stream>>>(n, W, pn, n_nodes);
    edge_score_kernel<<<eblk, 256, 0, stream>>>(e, W, bias, pn, src, dst, out, n_edges);
}

// Round 4
// 82.527 us; speedup vs baseline: 3.3110x; 3.3110x over previous
//
#include <hip/hip_runtime.h>
#include <math.h>

#define D_FEAT 128
#define D_DOT  4

// Layout: 16 lanes per row; lane `sub` (0..15) owns float4 cols sub and sub+16
// of its row. Each wave processes 8 rows per pass as two independent groups of
// 4 (unroll x2): 4 coalesced load instrs in flight, two independent 4-deep
// shuffle-reduce trees that interleave. W (8 float4/lane) hoisted to registers.
// Exact grid: one pass per wave, no loop.

__device__ __forceinline__ float dot4(const float4 a, const float4 b) {
    return a.x * b.x + a.y * b.y + a.z * b.z + a.w * b.w;
}

__global__ __launch_bounds__(256, 6) void node_proj_kernel(
    const float* __restrict__ n,
    const float* __restrict__ W,
    float* __restrict__ pn,
    int n_nodes)
{
    const int t    = threadIdx.x;
    const int lane = t & 63;
    const int sub  = lane & 15;
    const int g    = lane >> 4;            // 0..3
    const int wave = t >> 6;               // 0..3
    const int base = blockIdx.x * 32 + wave * 8;
    const int last = n_nodes - 1;

    const float4* W4 = reinterpret_cast<const float4*>(W);
    float4 wlo[D_DOT], whi[D_DOT];
#pragma unroll
    for (int k = 0; k < D_DOT; ++k) {
        wlo[k] = W4[k * 32 + sub];
        whi[k] = W4[k * 32 + sub + 16];
    }

    const int rA = base + g;
    const int rB = base + 4 + g;
    const int cA = rA > last ? last : rA;
    const int cB = rB > last ? last : rB;
    const float4* pA = reinterpret_cast<const float4*>(n) + (size_t)cA * 32;
    const float4* pB = reinterpret_cast<const float4*>(n) + (size_t)cB * 32;
    const float4 xAl = pA[sub], xAh = pA[sub + 16];
    const float4 xBl = pB[sub], xBh = pB[sub + 16];

    float a[D_DOT], c[D_DOT];
#pragma unroll
    for (int k = 0; k < D_DOT; ++k) {
        a[k] = dot4(xAl, wlo[k]) + dot4(xAh, whi[k]);
        c[k] = dot4(xBl, wlo[k]) + dot4(xBh, whi[k]);
    }
#pragma unroll
    for (int m = 8; m >= 1; m >>= 1) {
#pragma unroll
        for (int k = 0; k < D_DOT; ++k) {
            a[k] += __shfl_xor(a[k], m, 64);
            c[k] += __shfl_xor(c[k], m, 64);
        }
    }
    if (sub == 0 && rA < n_nodes)
        reinterpret_cast<float4*>(pn)[rA] = make_float4(a[0], a[1], a[2], a[3]);
    if (sub == 0 && rB < n_nodes)
        reinterpret_cast<float4*>(pn)[rB] = make_float4(c[0], c[1], c[2], c[3]);
}

__global__ __launch_bounds__(256, 6) void edge_score_kernel(
    const float* __restrict__ e,
    const float* __restrict__ W,
    const float* __restrict__ bias,
    const float* __restrict__ pn,
    const int* __restrict__ src_idx,
    const int* __restrict__ dst_idx,
    float* __restrict__ out,
    int n_edges)
{
    const int t    = threadIdx.x;
    const int lane = t & 63;
    const int sub  = lane & 15;
    const int g    = lane >> 4;
    const int wave = t >> 6;
    const int base = blockIdx.x * 32 + wave * 8;
    const int last = n_edges - 1;

    const float4* W4 = reinterpret_cast<const float4*>(W);
    float4 wlo[D_DOT], whi[D_DOT];
#pragma unroll
    for (int k = 0; k < D_DOT; ++k) {
        wlo[k] = W4[k * 32 + sub];
        whi[k] = W4[k * 32 + sub + 16];
    }
    const float b0 = bias[0], b1 = bias[1], b2 = bias[2], b3 = bias[3];

    const int rA = base + g;
    const int rB = base + 4 + g;
    const int cA = rA > last ? last : rA;
    const int cB = rB > last ? last : rB;
    const float4* pAp = reinterpret_cast<const float4*>(e) + (size_t)cA * 32;
    const float4* pBp = reinterpret_cast<const float4*>(e) + (size_t)cB * 32;
    const float4 xAl = pAp[sub], xAh = pAp[sub + 16];
    const float4 xBl = pBp[sub], xBh = pBp[sub + 16];

    float a[D_DOT], c[D_DOT];
#pragma unroll
    for (int k = 0; k < D_DOT; ++k) {
        a[k] = dot4(xAl, wlo[k]) + dot4(xAh, whi[k]);
        c[k] = dot4(xBl, wlo[k]) + dot4(xBh, whi[k]);
    }
#pragma unroll
    for (int m = 8; m >= 1; m >>= 1) {
#pragma unroll
        for (int k = 0; k < D_DOT; ++k) {
            a[k] += __shfl_xor(a[k], m, 64);
            c[k] += __shfl_xor(c[k], m, 64);
        }
    }

    if (sub == 0 && rA < n_edges) {
        const int s = src_idx[rA];
        const int d = dst_idx[rA];
        const float4 ps = reinterpret_cast<const float4*>(pn)[s];
        const float4 pd = reinterpret_cast<const float4*>(pn)[d];
        const float u0 = 0.5f * a[0] + b0, u1 = 0.5f * a[1] + b1;
        const float u2 = 0.5f * a[2] + b2, u3 = 0.5f * a[3] + b3;
        float dot = (0.5f * ps.x + u0) * (0.5f * pd.x + u0)
                  + (0.5f * ps.y + u1) * (0.5f * pd.y + u1)
                  + (0.5f * ps.z + u2) * (0.5f * pd.z + u2)
                  + (0.5f * ps.w + u3) * (0.5f * pd.w + u3);
        out[rA] = 1.0f / (1.0f + __expf(-dot));
    }
    if (sub == 0 && rB < n_edges) {
        const int s = src_idx[rB];
        const int d = dst_idx[rB];
        const float4 ps = reinterpret_cast<const float4*>(pn)[s];
        const float4 pd = reinterpret_cast<const float4*>(pn)[d];
        const float u0 = 0.5f * c[0] + b0, u1 = 0.5f * c[1] + b1;
        const float u2 = 0.5f * c[2] + b2, u3 = 0.5f * c[3] + b3;
        float dot = (0.5f * ps.x + u0) * (0.5f * pd.x + u0)
                  + (0.5f * ps.y + u1) * (0.5f * pd.y + u1)
                  + (0.5f * ps.z + u2) * (0.5f * pd.z + u2)
                  + (0.5f * ps.w + u3) * (0.5f * pd.w + u3);
        out[rB] = 1.0f / (1.0f + __expf(-dot));
    }
}

extern "C" void kernel_launch(void* const* d_in, const int* in_sizes, int n_in,
                              void* d_out, int out_size, void* d_ws, size_t ws_size,
                              hipStream_t stream) {
    const float* n    = (const float*)d_in[0];
    const float* e    = (const float*)d_in[1];
    const float* W    = (const float*)d_in[2];
    const float* bias = (const float*)d_in[3];
    const int*   src  = (const int*)d_in[4];
    const int*   dst  = (const int*)d_in[5];
    float* out = (float*)d_out;

    const int n_nodes = in_sizes[0] / D_FEAT;
    const int n_edges = in_sizes[1] / D_FEAT;

    float* pn = (float*)d_ws;  // n_nodes * 4 floats

    const int nblk = (n_nodes + 31) / 32;   // 32 rows per block
    const int eblk = (n_edges + 31) / 32;
    node_proj_kernel<<<nblk, 256, 0, stream>>>(n, W, pn, n_nodes);
    edge_score_kernel<<<eblk, 256, 0, stream>>>(e, W, bias, pn, src, dst, out, n_edges);
}

// Round 5
// 80.838 us; speedup vs baseline: 3.3802x; 1.0209x over previous
//
#include <hip/hip_runtime.h>
#include <math.h>

#define D_FEAT 128
#define D_DOT  4

// 16 lanes per row (groups align with DPP rows); 8 rows per wave (2 sets of 4).
// Reduction via DPP row_ror adds (pure VALU, no LDS pipe). Index loads and pn
// gathers issued at the top so their latency overlaps the row FMA work.

__device__ __forceinline__ float dot4(const float4 a, const float4 b) {
    return a.x * b.x + a.y * b.y + a.z * b.z + a.w * b.w;
}

template <int CTRL>
__device__ __forceinline__ float dpp_add(float x) {
    union { float f; int i; } u, v;
    u.f = x;
    v.i = __builtin_amdgcn_update_dpp(u.i, u.i, CTRL, 0xF, 0xF, true);
    return x + v.f;
}

// Sum across the 16 lanes of each DPP row; result in ALL lanes of the row.
__device__ __forceinline__ float row_reduce16(float x) {
    x = dpp_add<0x128>(x);  // row_ror:8
    x = dpp_add<0x124>(x);  // row_ror:4
    x = dpp_add<0x122>(x);  // row_ror:2
    x = dpp_add<0x121>(x);  // row_ror:1
    return x;
}

__global__ __launch_bounds__(256, 4) void node_proj_kernel(
    const float* __restrict__ n,
    const float* __restrict__ W,
    float* __restrict__ pn,
    int n_nodes)
{
    const int t    = threadIdx.x;
    const int lane = t & 63;
    const int sub  = lane & 15;
    const int g    = lane >> 4;
    const int wave = t >> 6;
    const int base = blockIdx.x * 32 + wave * 8;
    const int last = n_nodes - 1;

    const int rA = base + g;
    const int rB = base + 4 + g;
    const int cA = rA > last ? last : rA;
    const int cB = rB > last ? last : rB;

    const float4* n4 = reinterpret_cast<const float4*>(n);
    const float4 xAl = n4[(size_t)cA * 32 + sub], xAh = n4[(size_t)cA * 32 + sub + 16];
    const float4 xBl = n4[(size_t)cB * 32 + sub], xBh = n4[(size_t)cB * 32 + sub + 16];

    const float4* W4 = reinterpret_cast<const float4*>(W);
    float4 wlo[D_DOT], whi[D_DOT];
#pragma unroll
    for (int k = 0; k < D_DOT; ++k) {
        wlo[k] = W4[k * 32 + sub];
        whi[k] = W4[k * 32 + sub + 16];
    }

    float a[D_DOT], c[D_DOT];
#pragma unroll
    for (int k = 0; k < D_DOT; ++k) {
        a[k] = dot4(xAl, wlo[k]) + dot4(xAh, whi[k]);
        c[k] = dot4(xBl, wlo[k]) + dot4(xBh, whi[k]);
    }
#pragma unroll
    for (int k = 0; k < D_DOT; ++k) {
        a[k] = row_reduce16(a[k]);
        c[k] = row_reduce16(c[k]);
    }

    if (sub == 0 && rA < n_nodes)
        reinterpret_cast<float4*>(pn)[rA] = make_float4(a[0], a[1], a[2], a[3]);
    if (sub == 0 && rB < n_nodes)
        reinterpret_cast<float4*>(pn)[rB] = make_float4(c[0], c[1], c[2], c[3]);
}

__global__ __launch_bounds__(256, 4) void edge_score_kernel(
    const float* __restrict__ e,
    const float* __restrict__ W,
    const float* __restrict__ bias,
    const float* __restrict__ pn,
    const int* __restrict__ src_idx,
    const int* __restrict__ dst_idx,
    float* __restrict__ out,
    int n_edges)
{
    const int t    = threadIdx.x;
    const int lane = t & 63;
    const int sub  = lane & 15;
    const int g    = lane >> 4;
    const int wave = t >> 6;
    const int base = blockIdx.x * 32 + wave * 8;
    const int last = n_edges - 1;

    const int rA = base + g;
    const int rB = base + 4 + g;
    const int cA = rA > last ? last : rA;
    const int cB = rB > last ? last : rB;

    // --- issue idx loads first (group-uniform addresses -> broadcast) ---
    const int sA = src_idx[cA], dA = dst_idx[cA];
    const int sB = src_idx[cB], dB = dst_idx[cB];

    // --- dependent pn gathers issued early, overlap with row work below ---
    const float4* pn4 = reinterpret_cast<const float4*>(pn);
    const float4 psA = pn4[sA], pdA = pn4[dA];
    const float4 psB = pn4[sB], pdB = pn4[dB];

    // --- row data (coalesced) ---
    const float4* e4 = reinterpret_cast<const float4*>(e);
    const float4 xAl = e4[(size_t)cA * 32 + sub], xAh = e4[(size_t)cA * 32 + sub + 16];
    const float4 xBl = e4[(size_t)cB * 32 + sub], xBh = e4[(size_t)cB * 32 + sub + 16];

    const float4* W4 = reinterpret_cast<const float4*>(W);
    float4 wlo[D_DOT], whi[D_DOT];
#pragma unroll
    for (int k = 0; k < D_DOT; ++k) {
        wlo[k] = W4[k * 32 + sub];
        whi[k] = W4[k * 32 + sub + 16];
    }
    const float b0 = bias[0], b1 = bias[1], b2 = bias[2], b3 = bias[3];

    float a[D_DOT], c[D_DOT];
#pragma unroll
    for (int k = 0; k < D_DOT; ++k) {
        a[k] = dot4(xAl, wlo[k]) + dot4(xAh, whi[k]);
        c[k] = dot4(xBl, wlo[k]) + dot4(xBh, whi[k]);
    }
#pragma unroll
    for (int k = 0; k < D_DOT; ++k) {
        a[k] = row_reduce16(a[k]);
        c[k] = row_reduce16(c[k]);
    }

    // every lane holds the full sums; compute redundantly, store from sub==0
    {
        const float u0 = 0.5f * a[0] + b0, u1 = 0.5f * a[1] + b1;
        const float u2 = 0.5f * a[2] + b2, u3 = 0.5f * a[3] + b3;
        const float dot = (0.5f * psA.x + u0) * (0.5f * pdA.x + u0)
                        + (0.5f * psA.y + u1) * (0.5f * pdA.y + u1)
                        + (0.5f * psA.z + u2) * (0.5f * pdA.z + u2)
                        + (0.5f * psA.w + u3) * (0.5f * pdA.w + u3);
        if (sub == 0 && rA < n_edges)
            out[rA] = 1.0f / (1.0f + __expf(-dot));
    }
    {
        const float u0 = 0.5f * c[0] + b0, u1 = 0.5f * c[1] + b1;
        const float u2 = 0.5f * c[2] + b2, u3 = 0.5f * c[3] + b3;
        const float dot = (0.5f * psB.x + u0) * (0.5f * pdB.x + u0)
                        + (0.5f * psB.y + u1) * (0.5f * pdB.y + u1)
                        + (0.5f * psB.z + u2) * (0.5f * pdB.z + u2)
                        + (0.5f * psB.w + u3) * (0.5f * pdB.w + u3);
        if (sub == 0 && rB < n_edges)
            out[rB] = 1.0f / (1.0f + __expf(-dot));
    }
}

extern "C" void kernel_launch(void* const* d_in, const int* in_sizes, int n_in,
                              void* d_out, int out_size, void* d_ws, size_t ws_size,
                              hipStream_t stream) {
    const float* n    = (const float*)d_in[0];
    const float* e    = (const float*)d_in[1];
    const float* W    = (const float*)d_in[2];
    const float* bias = (const float*)d_in[3];
    const int*   src  = (const int*)d_in[4];
    const int*   dst  = (const int*)d_in[5];
    float* out = (float*)d_out;

    const int n_nodes = in_sizes[0] / D_FEAT;
    const int n_edges = in_sizes[1] / D_FEAT;

    float* pn = (float*)d_ws;  // n_nodes * 4 floats

    const int nblk = (n_nodes + 31) / 32;   // 32 rows per block
    const int eblk = (n_edges + 31) / 32;   // 600000/32 = 18750 exact
    node_proj_kernel<<<nblk, 256, 0, stream>>>(n, W, pn, n_nodes);
    edge_score_kernel<<<eblk, 256, 0, stream>>>(e, W, bias, pn, src, dst, out, n_edges);
}

// Round 6
// 77.777 us; speedup vs baseline: 3.5132x; 1.0393x over previous
//
#include <hip/hip_runtime.h>
#include <math.h>

#define D_FEAT 128
#define D_DOT  4

// 16 lanes per row (aligned with DPP rows); 12 rows per wave as 3 independent
// groups of 4 (amortizes the W-register prologue, triples in-flight row loads
// per wave). DPP row_ror reduction (pure VALU). 48 rows per block; edge grid
// exact (600000 = 48*12500).

__device__ __forceinline__ float dot4(const float4 a, const float4 b) {
    return a.x * b.x + a.y * b.y + a.z * b.z + a.w * b.w;
}

template <int CTRL>
__device__ __forceinline__ float dpp_add(float x) {
    union { float f; int i; } u, v;
    u.f = x;
    v.i = __builtin_amdgcn_update_dpp(u.i, u.i, CTRL, 0xF, 0xF, true);
    return x + v.f;
}

__device__ __forceinline__ float row_reduce16(float x) {
    x = dpp_add<0x128>(x);  // row_ror:8
    x = dpp_add<0x124>(x);  // row_ror:4
    x = dpp_add<0x122>(x);  // row_ror:2
    x = dpp_add<0x121>(x);  // row_ror:1
    return x;
}

__global__ __launch_bounds__(256, 4) void node_proj_kernel(
    const float* __restrict__ n,
    const float* __restrict__ W,
    float* __restrict__ pn,
    int n_nodes)
{
    const int t    = threadIdx.x;
    const int lane = t & 63;
    const int sub  = lane & 15;
    const int g    = lane >> 4;
    const int wave = t >> 6;
    const int base = blockIdx.x * 48 + wave * 12;
    const int last = n_nodes - 1;

    int r[3], c[3];
#pragma unroll
    for (int i = 0; i < 3; ++i) {
        r[i] = base + i * 4 + g;
        c[i] = r[i] > last ? last : r[i];
    }

    const float4* n4 = reinterpret_cast<const float4*>(n);
    float4 xl[3], xh[3];
#pragma unroll
    for (int i = 0; i < 3; ++i) {
        xl[i] = n4[(size_t)c[i] * 32 + sub];
        xh[i] = n4[(size_t)c[i] * 32 + sub + 16];
    }

    const float4* W4 = reinterpret_cast<const float4*>(W);
    float4 wlo[D_DOT], whi[D_DOT];
#pragma unroll
    for (int k = 0; k < D_DOT; ++k) {
        wlo[k] = W4[k * 32 + sub];
        whi[k] = W4[k * 32 + sub + 16];
    }

    float a[3][D_DOT];
#pragma unroll
    for (int i = 0; i < 3; ++i)
#pragma unroll
        for (int k = 0; k < D_DOT; ++k)
            a[i][k] = dot4(xl[i], wlo[k]) + dot4(xh[i], whi[k]);

#pragma unroll
    for (int i = 0; i < 3; ++i)
#pragma unroll
        for (int k = 0; k < D_DOT; ++k)
            a[i][k] = row_reduce16(a[i][k]);

#pragma unroll
    for (int i = 0; i < 3; ++i)
        if (sub == 0 && r[i] < n_nodes)
            reinterpret_cast<float4*>(pn)[r[i]] =
                make_float4(a[i][0], a[i][1], a[i][2], a[i][3]);
}

__global__ __launch_bounds__(256, 4) void edge_score_kernel(
    const float* __restrict__ e,
    const float* __restrict__ W,
    const float* __restrict__ bias,
    const float* __restrict__ pn,
    const int* __restrict__ src_idx,
    const int* __restrict__ dst_idx,
    float* __restrict__ out,
    int n_edges)
{
    const int t    = threadIdx.x;
    const int lane = t & 63;
    const int sub  = lane & 15;
    const int g    = lane >> 4;
    const int wave = t >> 6;
    const int base = blockIdx.x * 48 + wave * 12;
    const int last = n_edges - 1;

    int r[3], c[3];
#pragma unroll
    for (int i = 0; i < 3; ++i) {
        r[i] = base + i * 4 + g;
        c[i] = r[i] > last ? last : r[i];
    }

    // idx loads first (tiny, group-uniform), then the big row loads, then W;
    // pn gathers chain off idx and overlap the FMA/reduce work.
    int sI[3], dI[3];
#pragma unroll
    for (int i = 0; i < 3; ++i) { sI[i] = src_idx[c[i]]; dI[i] = dst_idx[c[i]]; }

    const float4* e4 = reinterpret_cast<const float4*>(e);
    float4 xl[3], xh[3];
#pragma unroll
    for (int i = 0; i < 3; ++i) {
        xl[i] = e4[(size_t)c[i] * 32 + sub];
        xh[i] = e4[(size_t)c[i] * 32 + sub + 16];
    }

    const float4* W4 = reinterpret_cast<const float4*>(W);
    float4 wlo[D_DOT], whi[D_DOT];
#pragma unroll
    for (int k = 0; k < D_DOT; ++k) {
        wlo[k] = W4[k * 32 + sub];
        whi[k] = W4[k * 32 + sub + 16];
    }
    const float b0 = bias[0], b1 = bias[1], b2 = bias[2], b3 = bias[3];

    const float4* pn4 = reinterpret_cast<const float4*>(pn);
    float4 ps[3], pd[3];
#pragma unroll
    for (int i = 0; i < 3; ++i) { ps[i] = pn4[sI[i]]; pd[i] = pn4[dI[i]]; }

    float a[3][D_DOT];
#pragma unroll
    for (int i = 0; i < 3; ++i)
#pragma unroll
        for (int k = 0; k < D_DOT; ++k)
            a[i][k] = dot4(xl[i], wlo[k]) + dot4(xh[i], whi[k]);

#pragma unroll
    for (int i = 0; i < 3; ++i)
#pragma unroll
        for (int k = 0; k < D_DOT; ++k)
            a[i][k] = row_reduce16(a[i][k]);

#pragma unroll
    for (int i = 0; i < 3; ++i) {
        const float u0 = 0.5f * a[i][0] + b0, u1 = 0.5f * a[i][1] + b1;
        const float u2 = 0.5f * a[i][2] + b2, u3 = 0.5f * a[i][3] + b3;
        const float dot = (0.5f * ps[i].x + u0) * (0.5f * pd[i].x + u0)
                        + (0.5f * ps[i].y + u1) * (0.5f * pd[i].y + u1)
                        + (0.5f * ps[i].z + u2) * (0.5f * pd[i].z + u2)
                        + (0.5f * ps[i].w + u3) * (0.5f * pd[i].w + u3);
        if (sub == 0 && r[i] < n_edges)
            out[r[i]] = 1.0f / (1.0f + __expf(-dot));
    }
}

extern "C" void kernel_launch(void* const* d_in, const int* in_sizes, int n_in,
                              void* d_out, int out_size, void* d_ws, size_t ws_size,
                              hipStream_t stream) {
    const float* n    = (const float*)d_in[0];
    const float* e    = (const float*)d_in[1];
    const float* W    = (const float*)d_in[2];
    const float* bias = (const float*)d_in[3];
    const int*   src  = (const int*)d_in[4];
    const int*   dst  = (const int*)d_in[5];
    float* out = (float*)d_out;

    const int n_nodes = in_sizes[0] / D_FEAT;
    const int n_edges = in_sizes[1] / D_FEAT;

    float* pn = (float*)d_ws;  // n_nodes * 4 floats

    const int nblk = (n_nodes + 47) / 48;
    const int eblk = (n_edges + 47) / 48;   // 600000 / 48 = 12500 exact
    node_proj_kernel<<<nblk, 256, 0, stream>>>(n, W, pn, n_nodes);
    edge_score_kernel<<<eblk, 256, 0, stream>>>(e, W, bias, pn, src, dst, out, n_edges);
}